// Round 8
// baseline (541.402 us; speedup 1.0000x reference)
//
#include <hip/hip_runtime.h>
#include <cstdint>
#include <cstddef>

typedef __bf16 bf16;
typedef __bf16 bf16x8 __attribute__((ext_vector_type(8)));
typedef float  f32x4  __attribute__((ext_vector_type(4)));
typedef unsigned short u16;

#define MD ((size_t)8388608)   // 16384*512 elements

// ---- async global->LDS 16B copy. LDS dest = wave-uniform base + lane*16 ----
__device__ __forceinline__ void async_copy16(const bf16* gp, bf16* lp) {
  __builtin_amdgcn_global_load_lds(
      (__attribute__((address_space(1))) void*)(gp),
      (__attribute__((address_space(3))) void*)(lp), 16, 0, 0);
}

// ---- inline dtype probe: wave ballots the 64 even (low-half) u16s of X.
// fp32 mantissa halves are ~uniform -> P(all 64 exp<141) ~ 2e-17. ----
__device__ __forceinline__ int is_f32(const u16* __restrict__ x) {
  const int e = (x[(threadIdx.x & 63) * 2] >> 7) & 0xFF;
  return __ballot(e >= 141) != 0ull;
}

// =====================================================================
// Batched conversion of all 20 float tensors into bf16 staging in ws.
// =====================================================================
struct ConvSrc { const void* p[20]; };

__global__ __launch_bounds__(256)
void convert_all(ConvSrc s, bf16* __restrict__ ws, const u16* __restrict__ xprobe)
{
  const int n[20] = {8388608, 8388608,
                     262144, 262144, 262144, 262144, 262144, 262144, 262144, 262144,
                     1048576, 2048, 1048576, 512, 512, 512, 512, 512, 512, 512};
  const unsigned int doff[20] = {
      41943040u, 50331648u,
      58720256u, 58982400u, 59244544u, 59506688u,
      59768832u, 60030976u, 60293120u, 60555264u,
      60817408u, 61865984u, 61868032u, 62916608u,
      62917120u, 62917632u, 62918144u, 62918656u, 62919168u, 62919680u};

  const int f32 = is_f32(xprobe);

  int bi = blockIdx.x;
  int idx = 0, b0 = 0;
  for (; idx < 20; ++idx) {
    const int nb = (n[idx] + 2047) >> 11;
    if (bi < b0 + nb) break;
    b0 += nb;
  }
  const int i = ((bi - b0) << 11) + threadIdx.x * 8;
  if (i >= n[idx]) return;
  bf16* dst = ws + doff[idx] + i;
  if (f32) {
    const float* sp = (const float*)s.p[idx] + i;
    f32x4 a = *(const f32x4*)sp;
    f32x4 b = *(const f32x4*)(sp + 4);
    bf16x8 o;
#pragma unroll
    for (int e = 0; e < 4; ++e) { o[e] = (bf16)a[e]; o[4 + e] = (bf16)b[e]; }
    *(bf16x8*)dst = o;
  } else {
    *(bf16x8*)dst = *(const bf16x8*)((const bf16*)s.p[idx] + i);
  }
}

// =====================================================================
// GEMM v5: C[M,N] = act(A[M,K] @ B[N,K]^T + bias), bf16, fp32 accum.
// MODE 0: plain, MODE 1: bias+LeakyReLU(0.01), MODE 2: bias only.
// 64x128 tile, BK=64, XOR-swizzled LDS (conflict-free, verified r6),
// EXPLICIT DOUBLE BUFFER: stage(kt+1) is issued after the barrier and
// before compute(kt), so the barrier's vmcnt(0) drain only covers loads
// that had a full compute phase in flight (kills the r6/r7 barrier
// stall: MfmaUtil 23% / VALU 40% / HBM 28% = nothing saturated).
// LDS = 2*(64+128)*64*2B = 48 KB -> 3 blocks/CU. One barrier per K-iter.
// =====================================================================
template<int MODE, int TM, int TN>
__global__ __launch_bounds__(256)
void gemm_bt(const bf16* __restrict__ A, const bf16* __restrict__ B,
             const bf16* __restrict__ bias, bf16* __restrict__ C,
             int M, int N, int K)
{
  constexpr int MI = TM / 32;
  constexpr int NJ = TN / 32;
  constexpr int CA = TM / 32;   // A staging copies per thread
  constexpr int CB = TN / 32;
  __shared__ __attribute__((aligned(16))) bf16 As[2][TM * 64];
  __shared__ __attribute__((aligned(16))) bf16 Bs[2][TN * 64];

  const int t    = threadIdx.x;
  const int wave = t >> 6;
  const int lane = t & 63;
  const int quad = lane >> 4;
  const int l15  = lane & 15;
  const int wr   = (wave >> 1) * (TM / 2);
  const int wc   = (wave & 1) * (TN / 2);
  const int m0   = blockIdx.y * TM;
  const int n0   = blockIdx.x * TN;

  // ---- staging pointers (global src incl. loop-invariant swizzle) ----
  const bf16* gpa[CA];
  const bf16* gpb[CB];
#pragma unroll
  for (int c = 0; c < CA; ++c) {
    const int s   = c * 256 + t;
    const int row = s >> 3;
    const int kg  = ((s & 7) ^ (row & 7)) << 3;
    gpa[c] = A + (size_t)(m0 + row) * K + kg;
  }
#pragma unroll
  for (int c = 0; c < CB; ++c) {
    const int s   = c * 256 + t;
    const int row = s >> 3;
    const int kg  = ((s & 7) ^ (row & 7)) << 3;
    gpb[c] = B + (size_t)(n0 + row) * K + kg;
  }

  auto stage = [&](bf16* dA, bf16* dB) {
#pragma unroll
    for (int c = 0; c < CA; ++c) {
      async_copy16(gpa[c], dA + ((c * 256 + wave * 64) << 3));
      gpa[c] += 64;
    }
#pragma unroll
    for (int c = 0; c < CB; ++c) {
      async_copy16(gpb[c], dB + ((c * 256 + wave * 64) << 3));
      gpb[c] += 64;
    }
  };

  const f32x4 fz = {0.f, 0.f, 0.f, 0.f};
  f32x4 acc[MI][NJ];
#pragma unroll
  for (int i = 0; i < MI; ++i)
#pragma unroll
    for (int j = 0; j < NJ; ++j) acc[i][j] = fz;

  auto compute = [&](const bf16* sA, const bf16* sB) {
#pragma unroll
    for (int ks = 0; ks < 2; ++ks) {
      bf16x8 af[MI], bfv[NJ];
#pragma unroll
      for (int i = 0; i < MI; ++i) {
        const int row = wr + i * 16 + l15;
        const int ph  = (ks * 4 + quad) ^ (row & 7);
        af[i] = *(const bf16x8*)(sA + row * 64 + ph * 8);
      }
#pragma unroll
      for (int j = 0; j < NJ; ++j) {
        const int row = wc + j * 16 + l15;
        const int ph  = (ks * 4 + quad) ^ (row & 7);
        bfv[j] = *(const bf16x8*)(sB + row * 64 + ph * 8);
      }
#pragma unroll
      for (int i = 0; i < MI; ++i)
#pragma unroll
        for (int j = 0; j < NJ; ++j)
          acc[i][j] = __builtin_amdgcn_mfma_f32_16x16x32_bf16(af[i], bfv[j],
                                                              acc[i][j], 0, 0, 0);
    }
  };

  // ---- pipelined K-loop (nkt is even: K in {512, 2048}) ----
  const int nkt = K >> 6;
  stage(As[0], Bs[0]);
  for (int kt = 0; kt < nkt; kt += 2) {
    __syncthreads();                    // drains stage(kt) [in flight 1 phase]
    stage(As[1], Bs[1]);                // kt+1 < nkt always (nkt even)
    compute(As[0], Bs[0]);
    __syncthreads();                    // drains stage(kt+1)
    if (kt + 2 < nkt) stage(As[0], Bs[0]);
    compute(As[1], Bs[1]);
  }

#pragma unroll
  for (int i = 0; i < MI; ++i) {
    const int m = m0 + wr + i * 16 + quad * 4;
#pragma unroll
    for (int j = 0; j < NJ; ++j) {
      const int n = n0 + wc + j * 16 + l15;
      float bv = 0.f;
      if (MODE >= 1) bv = (float)bias[n];
#pragma unroll
      for (int r = 0; r < 4; ++r) {
        float v = acc[i][j][r];
        if (MODE >= 1) v += bv;
        if (MODE == 1) v = v > 0.f ? v : 0.01f * v;
        C[(size_t)(m + r) * N + n] = (bf16)v;
      }
    }
  }
}

// =====================================================================
// Flash attention v3.1 (unchanged from r7): static softmax, XCD-aware
// block map (same-(b,h) q-tiles differ by 256 in blockIdx -> same XCD).
// =====================================================================
__global__ __launch_bounds__(256, 4)
void flash_attn(const bf16* __restrict__ Qp, const bf16* __restrict__ Kp,
                const bf16* __restrict__ Vp, bf16* __restrict__ Op,
                const int* __restrict__ vlen, int per_query, int sq, int skv)
{
  __shared__ __attribute__((aligned(16))) bf16 Ks[64][72];
  __shared__ __attribute__((aligned(16))) bf16 VsT[64][72];   // [d][k]
  __shared__ __attribute__((aligned(16))) bf16 Ps[4][32][72]; // per-wave [q][k]
  __shared__ int vlmax_sh;

  const int t    = threadIdx.x;
  const int wave = t >> 6;
  const int lane = t & 63;
  const int quad = lane >> 4;
  const int l15  = lane & 15;
  const int bx   = blockIdx.x;
  const int qt   = bx >> 8;          // 0..3 (slowest)
  const int h    = bx & 7;
  const int b    = (bx >> 3) & 31;
  const int q0   = qt * 128 + wave * 32;

  bf16x8 qfrag[2][2];
#pragma unroll
  for (int mt = 0; mt < 2; ++mt)
#pragma unroll
    for (int ks = 0; ks < 2; ++ks)
      qfrag[mt][ks] = *(const bf16x8*)(Qp +
          (size_t)(b * 512 + q0 + mt * 16 + l15) * sq + h * 64 + ks * 32 + quad * 8);

  int vl_r[2][4];
  int myvl = 1;
#pragma unroll
  for (int mt = 0; mt < 2; ++mt)
#pragma unroll
    for (int r = 0; r < 4; ++r) {
      const int q = q0 + mt * 16 + quad * 4 + r;
      const int v = per_query ? vlen[b * 512 + q] : vlen[b];
      vl_r[mt][r] = v;
      myvl = v > myvl ? v : myvl;
    }

  if (t == 0) vlmax_sh = 1;
  __syncthreads();
#pragma unroll
  for (int off = 1; off < 64; off <<= 1) {
    const int o = __shfl_xor(myvl, off);
    myvl = o > myvl ? o : myvl;
  }
  if (lane == 0) atomicMax(&vlmax_sh, myvl);
  __syncthreads();
  const int ktiles = (vlmax_sh + 63) >> 6;

  const f32x4 fz = {0.f, 0.f, 0.f, 0.f};
  float l_part[2][4] = {{0.f,0.f,0.f,0.f},{0.f,0.f,0.f,0.f}};
  f32x4 o_acc[2][4];
#pragma unroll
  for (int mt = 0; mt < 2; ++mt)
#pragma unroll
    for (int nt = 0; nt < 4; ++nt) o_acc[mt][nt] = fz;

  for (int kt = 0; kt < ktiles; ++kt) {
    const int k0 = kt * 64;
    __syncthreads();   // prior K/V tiles fully consumed
    {
      const int r0 = t >> 3;
      const int c0 = (t & 7) * 8;
      const bf16* g = Kp + (size_t)(b * 512 + k0 + r0) * skv + h * 64 + c0;
      *(bf16x8*)&Ks[r0][c0]      = *(const bf16x8*)g;
      *(bf16x8*)&Ks[r0 + 32][c0] = *(const bf16x8*)(g + (size_t)32 * skv);
    }
    {
      const bf16* g = Vp + (size_t)(b * 512 + k0 + wave * 16) * skv + h * 64 + lane;
      bf16x8 lo, hi;
#pragma unroll
      for (int kk = 0; kk < 8; ++kk) lo[kk] = g[(size_t)kk * skv];
#pragma unroll
      for (int kk = 0; kk < 8; ++kk) hi[kk] = g[(size_t)(kk + 8) * skv];
      *(bf16x8*)&VsT[lane][wave * 16]     = lo;
      *(bf16x8*)&VsT[lane][wave * 16 + 8] = hi;
    }
    __syncthreads();

    // ---- QK^T ----
    f32x4 s[2][4];
#pragma unroll
    for (int mt = 0; mt < 2; ++mt)
#pragma unroll
      for (int nt = 0; nt < 4; ++nt) s[mt][nt] = fz;
#pragma unroll
    for (int ks = 0; ks < 2; ++ks)
#pragma unroll
      for (int nt = 0; nt < 4; ++nt) {
        const bf16x8 bk = *(const bf16x8*)&Ks[nt * 16 + l15][ks * 32 + quad * 8];
        s[0][nt] = __builtin_amdgcn_mfma_f32_16x16x32_bf16(qfrag[0][ks], bk, s[0][nt], 0, 0, 0);
        s[1][nt] = __builtin_amdgcn_mfma_f32_16x16x32_bf16(qfrag[1][ks], bk, s[1][nt], 0, 0, 0);
      }

    // ---- static softmax: p = masked ? 0 : exp(s/8); accumulate l ----
#pragma unroll
    for (int mt = 0; mt < 2; ++mt)
#pragma unroll
      for (int nt = 0; nt < 4; ++nt) {
        const int k_abs = k0 + nt * 16 + l15;
#pragma unroll
        for (int r = 0; r < 4; ++r) {
          const float p = (k_abs < vl_r[mt][r]) ? __expf(s[mt][nt][r] * 0.125f) : 0.f;
          l_part[mt][r] += p;
          Ps[wave][mt * 16 + quad * 4 + r][nt * 16 + l15] = (bf16)p;
        }
      }

    // ---- O += P @ V (Ps is per-wave; same-wave DS ordering suffices) ----
#pragma unroll
    for (int ks = 0; ks < 2; ++ks) {
      const bf16x8 ap0 = *(const bf16x8*)&Ps[wave][l15][ks * 32 + quad * 8];
      const bf16x8 ap1 = *(const bf16x8*)&Ps[wave][16 + l15][ks * 32 + quad * 8];
#pragma unroll
      for (int nt = 0; nt < 4; ++nt) {
        const bf16x8 bv = *(const bf16x8*)&VsT[nt * 16 + l15][ks * 32 + quad * 8];
        o_acc[0][nt] = __builtin_amdgcn_mfma_f32_16x16x32_bf16(ap0, bv, o_acc[0][nt], 0, 0, 0);
        o_acc[1][nt] = __builtin_amdgcn_mfma_f32_16x16x32_bf16(ap1, bv, o_acc[1][nt], 0, 0, 0);
      }
    }
  }

  // ---- epilogue ----
#pragma unroll
  for (int mt = 0; mt < 2; ++mt)
#pragma unroll
    for (int r = 0; r < 4; ++r) {
      float l = l_part[mt][r];
#pragma unroll
      for (int off = 1; off < 16; off <<= 1)
        l += __shfl_xor(l, off);
      const float inv_l = (l > 0.f) ? (1.f / l) : 0.f;
      const int q = q0 + mt * 16 + quad * 4 + r;
#pragma unroll
      for (int nt = 0; nt < 4; ++nt)
        Op[(size_t)(b * 512 + q) * 512 + h * 64 + nt * 16 + l15] =
            (bf16)(o_acc[mt][nt][r] * inv_l);
    }
}

// =====================================================================
// AddNorm (internal, bf16 out). One wave per 512-row. In-place safe.
// =====================================================================
__global__ __launch_bounds__(256)
void add_layernorm(const bf16* X, const bf16* R,
                   const bf16* __restrict__ gamma, const bf16* __restrict__ beta,
                   bf16* Out)
{
  const int t    = threadIdx.x;
  const int wave = t >> 6;
  const int lane = t & 63;
  const size_t row  = (size_t)blockIdx.x * 4 + wave;
  const size_t base = row * 512 + lane * 8;

  bf16x8 xv = *(const bf16x8*)(X + base);
  bf16x8 rv = *(const bf16x8*)(R + base);
  float v[8];
  float sum = 0.f, ss = 0.f;
#pragma unroll
  for (int i = 0; i < 8; ++i) {
    v[i] = (float)xv[i] + (float)rv[i];
    sum += v[i];
    ss  += v[i] * v[i];
  }
#pragma unroll
  for (int off = 1; off < 64; off <<= 1) {
    sum += __shfl_xor(sum, off);
    ss  += __shfl_xor(ss, off);
  }
  const float mean = sum * (1.f / 512.f);
  const float var  = ss * (1.f / 512.f) - mean * mean;
  const float rstd = rsqrtf(var + 1e-5f);

  bf16x8 gv = *(const bf16x8*)(gamma + lane * 8);
  bf16x8 bv = *(const bf16x8*)(beta + lane * 8);
  bf16x8 ov;
#pragma unroll
  for (int i = 0; i < 8; ++i)
    ov[i] = (bf16)(((v[i] - mean) * rstd) * (float)gv[i] + (float)bv[i]);
  *(bf16x8*)(Out + base) = ov;
}

// =====================================================================
// Final AddNorm: writes d_out as fp32 or bf16 per the inline dtype probe.
// =====================================================================
__global__ __launch_bounds__(256)
void add_layernorm_out(const bf16* X, const bf16* R,
                       const bf16* __restrict__ gamma, const bf16* __restrict__ beta,
                       void* Out, const u16* __restrict__ xprobe)
{
  const int t    = threadIdx.x;
  const int wave = t >> 6;
  const int lane = t & 63;
  const size_t row  = (size_t)blockIdx.x * 4 + wave;
  const size_t base = row * 512 + lane * 8;

  const int f32 = is_f32(xprobe);

  bf16x8 xv = *(const bf16x8*)(X + base);
  bf16x8 rv = *(const bf16x8*)(R + base);
  float v[8];
  float sum = 0.f, ss = 0.f;
#pragma unroll
  for (int i = 0; i < 8; ++i) {
    v[i] = (float)xv[i] + (float)rv[i];
    sum += v[i];
    ss  += v[i] * v[i];
  }
#pragma unroll
  for (int off = 1; off < 64; off <<= 1) {
    sum += __shfl_xor(sum, off);
    ss  += __shfl_xor(ss, off);
  }
  const float mean = sum * (1.f / 512.f);
  const float var  = ss * (1.f / 512.f) - mean * mean;
  const float rstd = rsqrtf(var + 1e-5f);

  bf16x8 gv = *(const bf16x8*)(gamma + lane * 8);
  bf16x8 bv = *(const bf16x8*)(beta + lane * 8);
  float o[8];
#pragma unroll
  for (int i = 0; i < 8; ++i)
    o[i] = ((v[i] - mean) * rstd) * (float)gv[i] + (float)bv[i];

  if (f32) {
    float* op = (float*)Out + base;
    f32x4 o0 = {o[0], o[1], o[2], o[3]};
    f32x4 o1 = {o[4], o[5], o[6], o[7]};
    *(f32x4*)op       = o0;
    *(f32x4*)(op + 4) = o1;
  } else {
    bf16x8 ov;
#pragma unroll
    for (int i = 0; i < 8; ++i) ov[i] = (bf16)o[i];
    *(bf16x8*)((bf16*)Out + base) = ov;
  }
}

// =====================================================================
extern "C" void kernel_launch(void* const* d_in, const int* in_sizes, int n_in,
                              void* d_out, int out_size, void* d_ws, size_t ws_size,
                              hipStream_t stream)
{
  (void)in_sizes; (void)n_in; (void)out_size; (void)ws_size;

  const int* dvl = (const int*)d_in[2];
  const int* evl = (const int*)d_in[3];
  const u16* xprobe = (const u16*)d_in[0];

  bf16* ws = (bf16*)d_ws;
  bf16* S0 = ws;                 // QKV packed / FFN hidden (S0..S3)
  bf16* S1 = ws + 1 * MD;
  bf16* S3 = ws + 3 * MD;        // attention output O
  bf16* S4 = ws + 4 * MD;        // Y then Z (in-place LN)
  bf16* Xb = ws + 5 * MD;        // X bf16; reused as FFN2 output
  bf16* Eb = ws + 6 * MD;
  bf16* W  = ws + 7 * MD;
  const bf16 *Wq1 = W,
             *Wo1 = W + 786432,   *Wq2 = W + 1048576, *Wk2 = W + 1310720,
             *Wo2 = W + 1835008,
             *W1  = W + 2097152,  *b1  = W + 3145728,
             *W2  = W + 3147776,  *b2  = W + 4196352,
             *g1  = W + 4196864,  *be1 = W + 4197376,
             *g2  = W + 4197888,  *be2 = W + 4198400,
             *g3  = W + 4198912,  *be3 = W + 4199424;

  // ---- ingest (dtype probe inlined per wave) ----
  ConvSrc cs;
  cs.p[0] = d_in[0];  cs.p[1] = d_in[1];
  for (int k = 0; k < 12; ++k) cs.p[2 + k] = d_in[4 + k];
  for (int k = 0; k < 6; ++k)  cs.p[14 + k] = d_in[16 + k];
  convert_all<<<dim3(10248), dim3(256), 0, stream>>>(cs, ws, xprobe);

  dim3 blk(256);
  dim3 gP(4, 256);     // N=512
  dim3 gQKV(12, 256);  // N=1536
  dim3 gKV(8, 256);    // N=1024
  dim3 gF1(16, 256);   // N=2048

  // ---- self-attention ----
  gemm_bt<0,64,128><<<gQKV, blk, 0, stream>>>(Xb, Wq1, nullptr, S0, 16384, 1536, 512);
  flash_attn<<<dim3(1024), blk, 0, stream>>>(S0, S0 + 512, S0 + 1024, S3, dvl, 1, 1536, 1536);
  gemm_bt<0,64,128><<<gP, blk, 0, stream>>>(S3, Wo1, nullptr, S1, 16384, 512, 512);
  add_layernorm<<<dim3(4096), blk, 0, stream>>>(Xb, S1, g1, be1, S4);   // Y

  // ---- cross-attention ----
  gemm_bt<0,64,128><<<gP,  blk, 0, stream>>>(S4, Wq2, nullptr, S0, 16384, 512, 512);
  gemm_bt<0,64,128><<<gKV, blk, 0, stream>>>(Eb, Wk2, nullptr, S1, 16384, 1024, 512);
  flash_attn<<<dim3(1024), blk, 0, stream>>>(S0, S1, S1 + 512, S3, evl, 0, 512, 1024);
  gemm_bt<0,64,128><<<gP, blk, 0, stream>>>(S3, Wo2, nullptr, S1, 16384, 512, 512);
  add_layernorm<<<dim3(4096), blk, 0, stream>>>(S4, S1, g2, be2, S4);   // Z

  // ---- FFN ----
  gemm_bt<1,64,128><<<gF1, blk, 0, stream>>>(S4, W1, b1, S0, 16384, 2048, 512);
  gemm_bt<2,64,128><<<gP,  blk, 0, stream>>>(S0, W2, b2, Xb, 16384, 512, 2048);
  add_layernorm_out<<<dim3(4096), blk, 0, stream>>>(S4, Xb, g3, be3, d_out, xprobe);
}

// Round 9
// 525.960 us; speedup vs baseline: 1.0294x; 1.0294x over previous
//
#include <hip/hip_runtime.h>
#include <cstdint>
#include <cstddef>

typedef __bf16 bf16;
typedef __bf16 bf16x8 __attribute__((ext_vector_type(8)));
typedef float  f32x4  __attribute__((ext_vector_type(4)));
typedef unsigned short u16;

#define MD ((size_t)8388608)   // 16384*512 elements

// ---- async global->LDS 16B copy. LDS dest = wave-uniform base + lane*16 ----
__device__ __forceinline__ void async_copy16(const bf16* gp, bf16* lp) {
  __builtin_amdgcn_global_load_lds(
      (__attribute__((address_space(1))) void*)(gp),
      (__attribute__((address_space(3))) void*)(lp), 16, 0, 0);
}

// ---- inline dtype probe: wave ballots the 64 even (low-half) u16s of X.
// fp32 mantissa halves are ~uniform -> P(all 64 exp<141) ~ 2e-17. ----
__device__ __forceinline__ int is_f32(const u16* __restrict__ x) {
  const int e = (x[(threadIdx.x & 63) * 2] >> 7) & 0xFF;
  return __ballot(e >= 141) != 0ull;
}

// =====================================================================
// Conversion of the 18 WEIGHT tensors into bf16 staging in ws.
// (X and enc are no longer materialized as bf16 — consumed raw.)
// =====================================================================
struct ConvSrc { const void* p[18]; };

__global__ __launch_bounds__(256)
void convert_all(ConvSrc s, bf16* __restrict__ ws, const u16* __restrict__ xprobe)
{
  const int n[18] = {262144, 262144, 262144, 262144, 262144, 262144, 262144, 262144,
                     1048576, 2048, 1048576, 512, 512, 512, 512, 512, 512, 512};
  const unsigned int doff[18] = {
      58720256u, 58982400u, 59244544u, 59506688u,
      59768832u, 60030976u, 60293120u, 60555264u,
      60817408u, 61865984u, 61868032u, 62916608u,
      62917120u, 62917632u, 62918144u, 62918656u, 62919168u, 62919680u};

  const int f32 = is_f32(xprobe);

  int bi = blockIdx.x;
  int idx = 0, b0 = 0;
  for (; idx < 18; ++idx) {
    const int nb = (n[idx] + 2047) >> 11;
    if (bi < b0 + nb) break;
    b0 += nb;
  }
  const int i = ((bi - b0) << 11) + threadIdx.x * 8;
  if (i >= n[idx]) return;
  bf16* dst = ws + doff[idx] + i;
  if (f32) {
    const float* sp = (const float*)s.p[idx] + i;
    f32x4 a = *(const f32x4*)sp;
    f32x4 b = *(const f32x4*)(sp + 4);
    bf16x8 o;
#pragma unroll
    for (int e = 0; e < 4; ++e) { o[e] = (bf16)a[e]; o[4 + e] = (bf16)b[e]; }
    *(bf16x8*)dst = o;
  } else {
    *(bf16x8*)dst = *(const bf16x8*)((const bf16*)s.p[idx] + i);
  }
}

// =====================================================================
// GEMM (r6-verified structure): C = act(A @ B^T + bias), fp32 accum.
// MODE 0: plain, 1: bias+LeakyReLU(0.01), 2: bias only.
// 128-tile, BK=64, XOR-swizzled LDS (SQ_LDS_BANK_CONFLICT=0, r6),
// single-buffered async global_load_lds staging (r6: best measured).
// AF32=1: A is a RAW input (fp32 or bf16 per device-side probe) —
// staged via registers + cvt + ds_write to the identical LDS layout.
// =====================================================================
template<int MODE, int TM, int TN, int AF32>
__global__ __launch_bounds__(256)
void gemm_bt(const void* __restrict__ Araw, const bf16* __restrict__ B,
             const bf16* __restrict__ bias, bf16* __restrict__ C,
             int M, int N, int K, const u16* __restrict__ xprobe)
{
  constexpr int MI = TM / 32;
  constexpr int NJ = TN / 32;
  constexpr int CA = TM / 32;
  constexpr int CB = TN / 32;
  __shared__ __attribute__((aligned(16))) bf16 As[TM * 64];
  __shared__ __attribute__((aligned(16))) bf16 Bs[TN * 64];

  const int t    = threadIdx.x;
  const int wave = t >> 6;
  const int lane = t & 63;
  const int quad = lane >> 4;
  const int l15  = lane & 15;
  const int wr   = (wave >> 1) * (TM / 2);
  const int wc   = (wave & 1) * (TN / 2);
  const int m0   = blockIdx.y * TM;
  const int n0   = blockIdx.x * TN;

  int af32 = 0;
  if (AF32) af32 = is_f32(xprobe);

  const f32x4 fz = {0.f, 0.f, 0.f, 0.f};
  f32x4 acc[MI][NJ];
#pragma unroll
  for (int i = 0; i < MI; ++i)
#pragma unroll
    for (int j = 0; j < NJ; ++j) acc[i][j] = fz;

  const int nkt = K >> 6;
  for (int kt = 0; kt < nkt; ++kt) {
    const int k0 = kt << 6;

    bf16x8 areg[CA];
    if (AF32) {
      // A -> registers (before barrier: no LDS hazard), cvt if fp32
#pragma unroll
      for (int c = 0; c < CA; ++c) {
        const int s   = c * 256 + t;
        const int row = s >> 3;
        const int kg  = ((s & 7) ^ (row & 7)) << 3;
        if (af32) {
          const float* g = (const float*)Araw + (size_t)(m0 + row) * K + k0 + kg;
          f32x4 lo = *(const f32x4*)g;
          f32x4 hi = *(const f32x4*)(g + 4);
#pragma unroll
          for (int e = 0; e < 4; ++e) { areg[c][e] = (bf16)lo[e]; areg[c][4 + e] = (bf16)hi[e]; }
        } else {
          areg[c] = *(const bf16x8*)((const bf16*)Araw + (size_t)(m0 + row) * K + k0 + kg);
        }
      }
    }

    __syncthreads();   // prior tile's LDS reads done

    if (AF32) {
#pragma unroll
      for (int c = 0; c < CA; ++c)
        *(bf16x8*)(As + (size_t)(c * 256 + t) * 8) = areg[c];
    } else {
#pragma unroll
      for (int c = 0; c < CA; ++c) {
        const int s   = c * 256 + t;
        const int row = s >> 3;
        const int kg  = ((s & 7) ^ (row & 7)) << 3;
        async_copy16((const bf16*)Araw + (size_t)(m0 + row) * K + k0 + kg,
                     As + ((c * 256 + wave * 64) << 3));
      }
    }
#pragma unroll
    for (int c = 0; c < CB; ++c) {
      const int s   = c * 256 + t;
      const int row = s >> 3;
      const int kg  = ((s & 7) ^ (row & 7)) << 3;
      async_copy16(B + (size_t)(n0 + row) * K + k0 + kg,
                   Bs + ((c * 256 + wave * 64) << 3));
    }
    __syncthreads();   // drains vmcnt (async B) + lgkm (A ds_write)

#pragma unroll
    for (int ks = 0; ks < 2; ++ks) {
      bf16x8 af[MI], bfv[NJ];
#pragma unroll
      for (int i = 0; i < MI; ++i) {
        const int row = wr + i * 16 + l15;
        const int ph  = (ks * 4 + quad) ^ (row & 7);
        af[i] = *(const bf16x8*)(As + row * 64 + ph * 8);
      }
#pragma unroll
      for (int j = 0; j < NJ; ++j) {
        const int row = wc + j * 16 + l15;
        const int ph  = (ks * 4 + quad) ^ (row & 7);
        bfv[j] = *(const bf16x8*)(Bs + row * 64 + ph * 8);
      }
#pragma unroll
      for (int i = 0; i < MI; ++i)
#pragma unroll
        for (int j = 0; j < NJ; ++j)
          acc[i][j] = __builtin_amdgcn_mfma_f32_16x16x32_bf16(af[i], bfv[j],
                                                              acc[i][j], 0, 0, 0);
    }
  }

#pragma unroll
  for (int i = 0; i < MI; ++i) {
    const int m = m0 + wr + i * 16 + quad * 4;
#pragma unroll
    for (int j = 0; j < NJ; ++j) {
      const int n = n0 + wc + j * 16 + l15;
      float bv = 0.f;
      if (MODE >= 1) bv = (float)bias[n];
#pragma unroll
      for (int r = 0; r < 4; ++r) {
        float v = acc[i][j][r];
        if (MODE >= 1) v += bv;
        if (MODE == 1) v = v > 0.f ? v : 0.01f * v;
        C[(size_t)(m + r) * N + n] = (bf16)v;
      }
    }
  }
}

// =====================================================================
// Flash attention v3.1 (r7, unchanged): static softmax, XCD-aware map.
// =====================================================================
__global__ __launch_bounds__(256, 4)
void flash_attn(const bf16* __restrict__ Qp, const bf16* __restrict__ Kp,
                const bf16* __restrict__ Vp, bf16* __restrict__ Op,
                const int* __restrict__ vlen, int per_query, int sq, int skv)
{
  __shared__ __attribute__((aligned(16))) bf16 Ks[64][72];
  __shared__ __attribute__((aligned(16))) bf16 VsT[64][72];   // [d][k]
  __shared__ __attribute__((aligned(16))) bf16 Ps[4][32][72]; // per-wave [q][k]
  __shared__ int vlmax_sh;

  const int t    = threadIdx.x;
  const int wave = t >> 6;
  const int lane = t & 63;
  const int quad = lane >> 4;
  const int l15  = lane & 15;
  const int bx   = blockIdx.x;
  const int qt   = bx >> 8;          // 0..3 (slowest)
  const int h    = bx & 7;
  const int b    = (bx >> 3) & 31;
  const int q0   = qt * 128 + wave * 32;

  bf16x8 qfrag[2][2];
#pragma unroll
  for (int mt = 0; mt < 2; ++mt)
#pragma unroll
    for (int ks = 0; ks < 2; ++ks)
      qfrag[mt][ks] = *(const bf16x8*)(Qp +
          (size_t)(b * 512 + q0 + mt * 16 + l15) * sq + h * 64 + ks * 32 + quad * 8);

  int vl_r[2][4];
  int myvl = 1;
#pragma unroll
  for (int mt = 0; mt < 2; ++mt)
#pragma unroll
    for (int r = 0; r < 4; ++r) {
      const int q = q0 + mt * 16 + quad * 4 + r;
      const int v = per_query ? vlen[b * 512 + q] : vlen[b];
      vl_r[mt][r] = v;
      myvl = v > myvl ? v : myvl;
    }

  if (t == 0) vlmax_sh = 1;
  __syncthreads();
#pragma unroll
  for (int off = 1; off < 64; off <<= 1) {
    const int o = __shfl_xor(myvl, off);
    myvl = o > myvl ? o : myvl;
  }
  if (lane == 0) atomicMax(&vlmax_sh, myvl);
  __syncthreads();
  const int ktiles = (vlmax_sh + 63) >> 6;

  const f32x4 fz = {0.f, 0.f, 0.f, 0.f};
  float l_part[2][4] = {{0.f,0.f,0.f,0.f},{0.f,0.f,0.f,0.f}};
  f32x4 o_acc[2][4];
#pragma unroll
  for (int mt = 0; mt < 2; ++mt)
#pragma unroll
    for (int nt = 0; nt < 4; ++nt) o_acc[mt][nt] = fz;

  for (int kt = 0; kt < ktiles; ++kt) {
    const int k0 = kt * 64;
    __syncthreads();   // prior K/V tiles fully consumed
    {
      const int r0 = t >> 3;
      const int c0 = (t & 7) * 8;
      const bf16* g = Kp + (size_t)(b * 512 + k0 + r0) * skv + h * 64 + c0;
      *(bf16x8*)&Ks[r0][c0]      = *(const bf16x8*)g;
      *(bf16x8*)&Ks[r0 + 32][c0] = *(const bf16x8*)(g + (size_t)32 * skv);
    }
    {
      const bf16* g = Vp + (size_t)(b * 512 + k0 + wave * 16) * skv + h * 64 + lane;
      bf16x8 lo, hi;
#pragma unroll
      for (int kk = 0; kk < 8; ++kk) lo[kk] = g[(size_t)kk * skv];
#pragma unroll
      for (int kk = 0; kk < 8; ++kk) hi[kk] = g[(size_t)(kk + 8) * skv];
      *(bf16x8*)&VsT[lane][wave * 16]     = lo;
      *(bf16x8*)&VsT[lane][wave * 16 + 8] = hi;
    }
    __syncthreads();

    // ---- QK^T ----
    f32x4 s[2][4];
#pragma unroll
    for (int mt = 0; mt < 2; ++mt)
#pragma unroll
      for (int nt = 0; nt < 4; ++nt) s[mt][nt] = fz;
#pragma unroll
    for (int ks = 0; ks < 2; ++ks)
#pragma unroll
      for (int nt = 0; nt < 4; ++nt) {
        const bf16x8 bk = *(const bf16x8*)&Ks[nt * 16 + l15][ks * 32 + quad * 8];
        s[0][nt] = __builtin_amdgcn_mfma_f32_16x16x32_bf16(qfrag[0][ks], bk, s[0][nt], 0, 0, 0);
        s[1][nt] = __builtin_amdgcn_mfma_f32_16x16x32_bf16(qfrag[1][ks], bk, s[1][nt], 0, 0, 0);
      }

    // ---- static softmax: p = masked ? 0 : exp(s/8); accumulate l ----
#pragma unroll
    for (int mt = 0; mt < 2; ++mt)
#pragma unroll
      for (int nt = 0; nt < 4; ++nt) {
        const int k_abs = k0 + nt * 16 + l15;
#pragma unroll
        for (int r = 0; r < 4; ++r) {
          const float p = (k_abs < vl_r[mt][r]) ? __expf(s[mt][nt][r] * 0.125f) : 0.f;
          l_part[mt][r] += p;
          Ps[wave][mt * 16 + quad * 4 + r][nt * 16 + l15] = (bf16)p;
        }
      }

    // ---- O += P @ V (Ps per-wave; same-wave DS ordering suffices) ----
#pragma unroll
    for (int ks = 0; ks < 2; ++ks) {
      const bf16x8 ap0 = *(const bf16x8*)&Ps[wave][l15][ks * 32 + quad * 8];
      const bf16x8 ap1 = *(const bf16x8*)&Ps[wave][16 + l15][ks * 32 + quad * 8];
#pragma unroll
      for (int nt = 0; nt < 4; ++nt) {
        const bf16x8 bv = *(const bf16x8*)&VsT[nt * 16 + l15][ks * 32 + quad * 8];
        o_acc[0][nt] = __builtin_amdgcn_mfma_f32_16x16x32_bf16(ap0, bv, o_acc[0][nt], 0, 0, 0);
        o_acc[1][nt] = __builtin_amdgcn_mfma_f32_16x16x32_bf16(ap1, bv, o_acc[1][nt], 0, 0, 0);
      }
    }
  }

  // ---- epilogue ----
#pragma unroll
  for (int mt = 0; mt < 2; ++mt)
#pragma unroll
    for (int r = 0; r < 4; ++r) {
      float l = l_part[mt][r];
#pragma unroll
      for (int off = 1; off < 16; off <<= 1)
        l += __shfl_xor(l, off);
      const float inv_l = (l > 0.f) ? (1.f / l) : 0.f;
      const int q = q0 + mt * 16 + quad * 4 + r;
#pragma unroll
      for (int nt = 0; nt < 4; ++nt)
        Op[(size_t)(b * 512 + q) * 512 + h * 64 + nt * 16 + l15] =
            (bf16)(o_acc[mt][nt][r] * inv_l);
    }
}

// =====================================================================
// AddNorm (internal, bf16 in/out). One wave per 512-row. In-place safe.
// =====================================================================
__global__ __launch_bounds__(256)
void add_layernorm(const bf16* X, const bf16* R,
                   const bf16* __restrict__ gamma, const bf16* __restrict__ beta,
                   bf16* Out)
{
  const int t    = threadIdx.x;
  const int wave = t >> 6;
  const int lane = t & 63;
  const size_t row  = (size_t)blockIdx.x * 4 + wave;
  const size_t base = row * 512 + lane * 8;

  bf16x8 xv = *(const bf16x8*)(X + base);
  bf16x8 rv = *(const bf16x8*)(R + base);
  float v[8];
  float sum = 0.f, ss = 0.f;
#pragma unroll
  for (int i = 0; i < 8; ++i) {
    v[i] = (float)xv[i] + (float)rv[i];
    sum += v[i];
    ss  += v[i] * v[i];
  }
#pragma unroll
  for (int off = 1; off < 64; off <<= 1) {
    sum += __shfl_xor(sum, off);
    ss  += __shfl_xor(ss, off);
  }
  const float mean = sum * (1.f / 512.f);
  const float var  = ss * (1.f / 512.f) - mean * mean;
  const float rstd = rsqrtf(var + 1e-5f);

  bf16x8 gv = *(const bf16x8*)(gamma + lane * 8);
  bf16x8 bv = *(const bf16x8*)(beta + lane * 8);
  bf16x8 ov;
#pragma unroll
  for (int i = 0; i < 8; ++i)
    ov[i] = (bf16)(((v[i] - mean) * rstd) * (float)gv[i] + (float)bv[i]);
  *(bf16x8*)(Out + base) = ov;
}

// =====================================================================
// AddNorm with RAW X (fp32 or bf16 per probe): used for AddNorm1.
// =====================================================================
__global__ __launch_bounds__(256)
void add_layernorm_x(const void* Xraw, const bf16* R,
                     const bf16* __restrict__ gamma, const bf16* __restrict__ beta,
                     bf16* Out, const u16* __restrict__ xprobe)
{
  const int t    = threadIdx.x;
  const int wave = t >> 6;
  const int lane = t & 63;
  const size_t row  = (size_t)blockIdx.x * 4 + wave;
  const size_t base = row * 512 + lane * 8;

  const int f32 = is_f32(xprobe);

  float v[8];
  if (f32) {
    const float* xp = (const float*)Xraw + base;
    f32x4 a = *(const f32x4*)xp;
    f32x4 b = *(const f32x4*)(xp + 4);
#pragma unroll
    for (int i = 0; i < 4; ++i) { v[i] = a[i]; v[4 + i] = b[i]; }
  } else {
    bf16x8 xv = *(const bf16x8*)((const bf16*)Xraw + base);
#pragma unroll
    for (int i = 0; i < 8; ++i) v[i] = (float)xv[i];
  }
  bf16x8 rv = *(const bf16x8*)(R + base);
  float sum = 0.f, ss = 0.f;
#pragma unroll
  for (int i = 0; i < 8; ++i) {
    v[i] += (float)rv[i];
    sum += v[i];
    ss  += v[i] * v[i];
  }
#pragma unroll
  for (int off = 1; off < 64; off <<= 1) {
    sum += __shfl_xor(sum, off);
    ss  += __shfl_xor(ss, off);
  }
  const float mean = sum * (1.f / 512.f);
  const float var  = ss * (1.f / 512.f) - mean * mean;
  const float rstd = rsqrtf(var + 1e-5f);

  bf16x8 gv = *(const bf16x8*)(gamma + lane * 8);
  bf16x8 bv = *(const bf16x8*)(beta + lane * 8);
  bf16x8 ov;
#pragma unroll
  for (int i = 0; i < 8; ++i)
    ov[i] = (bf16)(((v[i] - mean) * rstd) * (float)gv[i] + (float)bv[i]);
  *(bf16x8*)(Out + base) = ov;
}

// =====================================================================
// Final AddNorm: writes d_out as fp32 or bf16 per the inline dtype probe.
// =====================================================================
__global__ __launch_bounds__(256)
void add_layernorm_out(const bf16* X, const bf16* R,
                       const bf16* __restrict__ gamma, const bf16* __restrict__ beta,
                       void* Out, const u16* __restrict__ xprobe)
{
  const int t    = threadIdx.x;
  const int wave = t >> 6;
  const int lane = t & 63;
  const size_t row  = (size_t)blockIdx.x * 4 + wave;
  const size_t base = row * 512 + lane * 8;

  const int f32 = is_f32(xprobe);

  bf16x8 xv = *(const bf16x8*)(X + base);
  bf16x8 rv = *(const bf16x8*)(R + base);
  float v[8];
  float sum = 0.f, ss = 0.f;
#pragma unroll
  for (int i = 0; i < 8; ++i) {
    v[i] = (float)xv[i] + (float)rv[i];
    sum += v[i];
    ss  += v[i] * v[i];
  }
#pragma unroll
  for (int off = 1; off < 64; off <<= 1) {
    sum += __shfl_xor(sum, off);
    ss  += __shfl_xor(ss, off);
  }
  const float mean = sum * (1.f / 512.f);
  const float var  = ss * (1.f / 512.f) - mean * mean;
  const float rstd = rsqrtf(var + 1e-5f);

  bf16x8 gv = *(const bf16x8*)(gamma + lane * 8);
  bf16x8 bv = *(const bf16x8*)(beta + lane * 8);
  float o[8];
#pragma unroll
  for (int i = 0; i < 8; ++i)
    o[i] = ((v[i] - mean) * rstd) * (float)gv[i] + (float)bv[i];

  if (f32) {
    float* op = (float*)Out + base;
    f32x4 o0 = {o[0], o[1], o[2], o[3]};
    f32x4 o1 = {o[4], o[5], o[6], o[7]};
    *(f32x4*)op       = o0;
    *(f32x4*)(op + 4) = o1;
  } else {
    bf16x8 ov;
#pragma unroll
    for (int i = 0; i < 8; ++i) ov[i] = (bf16)o[i];
    *(bf16x8*)((bf16*)Out + base) = ov;
  }
}

// =====================================================================
extern "C" void kernel_launch(void* const* d_in, const int* in_sizes, int n_in,
                              void* d_out, int out_size, void* d_ws, size_t ws_size,
                              hipStream_t stream)
{
  (void)in_sizes; (void)n_in; (void)out_size; (void)ws_size;

  const int* dvl = (const int*)d_in[2];
  const int* evl = (const int*)d_in[3];
  const u16* xprobe = (const u16*)d_in[0];

  bf16* ws = (bf16*)d_ws;
  bf16* S0 = ws;                 // QKV packed / FFN hidden (S0..S3)
  bf16* S1 = ws + 1 * MD;
  bf16* S3 = ws + 3 * MD;        // attention output O
  bf16* S4 = ws + 4 * MD;        // Y then Z (in-place LN)
  bf16* Xb = ws + 5 * MD;        // FFN2 output temp
  bf16* W  = ws + 7 * MD;
  const bf16 *Wq1 = W,
             *Wo1 = W + 786432,   *Wq2 = W + 1048576, *Wk2 = W + 1310720,
             *Wo2 = W + 1835008,
             *W1  = W + 2097152,  *b1  = W + 3145728,
             *W2  = W + 3147776,  *b2  = W + 4196352,
             *g1  = W + 4196864,  *be1 = W + 4197376,
             *g2  = W + 4197888,  *be2 = W + 4198400,
             *g3  = W + 4198912,  *be3 = W + 4199424;

  // ---- ingest weights only (X/enc consumed raw) ----
  ConvSrc cs;
  for (int k = 0; k < 12; ++k) cs.p[k] = d_in[4 + k];
  for (int k = 0; k < 6; ++k)  cs.p[12 + k] = d_in[16 + k];
  convert_all<<<dim3(2056), dim3(256), 0, stream>>>(cs, ws, xprobe);

  dim3 blk(256);
  dim3 gP(4, 128);     // N=512
  dim3 gQKV(12, 128);  // N=1536
  dim3 gKV(8, 128);    // N=1024
  dim3 gF1(16, 128);   // N=2048

  // ---- self-attention ----
  gemm_bt<0,128,128,1><<<gQKV, blk, 0, stream>>>(d_in[0], Wq1, nullptr, S0, 16384, 1536, 512, xprobe);
  flash_attn<<<dim3(1024), blk, 0, stream>>>(S0, S0 + 512, S0 + 1024, S3, dvl, 1, 1536, 1536);
  gemm_bt<0,128,128,0><<<gP, blk, 0, stream>>>(S3, Wo1, nullptr, S1, 16384, 512, 512, xprobe);
  add_layernorm_x<<<dim3(4096), blk, 0, stream>>>(d_in[0], S1, g1, be1, S4, xprobe);  // Y

  // ---- cross-attention ----
  gemm_bt<0,128,128,0><<<gP,  blk, 0, stream>>>(S4, Wq2, nullptr, S0, 16384, 512, 512, xprobe);
  gemm_bt<0,128,128,1><<<gKV, blk, 0, stream>>>(d_in[1], Wk2, nullptr, S1, 16384, 1024, 512, xprobe);
  flash_attn<<<dim3(1024), blk, 0, stream>>>(S0, S1, S1 + 512, S3, evl, 0, 512, 1024);
  gemm_bt<0,128,128,0><<<gP, blk, 0, stream>>>(S3, Wo2, nullptr, S1, 16384, 512, 512, xprobe);
  add_layernorm<<<dim3(4096), blk, 0, stream>>>(S4, S1, g2, be2, S4);   // Z

  // ---- FFN ----
  gemm_bt<1,128,128,0><<<gF1, blk, 0, stream>>>(S4, W1, b1, S0, 16384, 2048, 512, xprobe);
  gemm_bt<2,128,128,0><<<gP,  blk, 0, stream>>>(S0, W2, b2, Xb, 16384, 512, 2048, xprobe);
  add_layernorm_out<<<dim3(4096), blk, 0, stream>>>(S4, Xb, g3, be3, d_out, xprobe);
}

// Round 10
// 461.458 us; speedup vs baseline: 1.1732x; 1.1398x over previous
//
#include <hip/hip_runtime.h>
#include <cstdint>
#include <cstddef>

typedef __bf16 bf16;
typedef __bf16 bf16x8 __attribute__((ext_vector_type(8)));
typedef float  f32x4  __attribute__((ext_vector_type(4)));
typedef unsigned short u16;

#define MD ((size_t)8388608)   // 16384*512 elements

// ---- async global->LDS 16B copy. LDS dest = wave-uniform base + lane*16 ----
__device__ __forceinline__ void async_copy16(const bf16* gp, bf16* lp) {
  __builtin_amdgcn_global_load_lds(
      (__attribute__((address_space(1))) void*)(gp),
      (__attribute__((address_space(3))) void*)(lp), 16, 0, 0);
}

// ---- inline dtype probe: wave ballots the 64 even (low-half) u16s of X.
// fp32 mantissa halves are ~uniform -> P(all 64 exp<141) ~ 2e-17. ----
__device__ __forceinline__ int is_f32(const u16* __restrict__ x) {
  const int e = (x[(threadIdx.x & 63) * 2] >> 7) & 0xFF;
  return __ballot(e >= 141) != 0ull;
}

// =====================================================================
// Batched conversion of all 20 float tensors into bf16 staging in ws.
// (r6 version — raw-fp32 GEMM consumption regressed in r9, reverted.)
// =====================================================================
struct ConvSrc { const void* p[20]; };

__global__ __launch_bounds__(256)
void convert_all(ConvSrc s, bf16* __restrict__ ws, const u16* __restrict__ xprobe)
{
  const int n[20] = {8388608, 8388608,
                     262144, 262144, 262144, 262144, 262144, 262144, 262144, 262144,
                     1048576, 2048, 1048576, 512, 512, 512, 512, 512, 512, 512};
  const unsigned int doff[20] = {
      41943040u, 50331648u,
      58720256u, 58982400u, 59244544u, 59506688u,
      59768832u, 60030976u, 60293120u, 60555264u,
      60817408u, 61865984u, 61868032u, 62916608u,
      62917120u, 62917632u, 62918144u, 62918656u, 62919168u, 62919680u};

  const int f32 = is_f32(xprobe);

  int bi = blockIdx.x;
  int idx = 0, b0 = 0;
  for (; idx < 20; ++idx) {
    const int nb = (n[idx] + 2047) >> 11;
    if (bi < b0 + nb) break;
    b0 += nb;
  }
  const int i = ((bi - b0) << 11) + threadIdx.x * 8;
  if (i >= n[idx]) return;
  bf16* dst = ws + doff[idx] + i;
  if (f32) {
    const float* sp = (const float*)s.p[idx] + i;
    f32x4 a = *(const f32x4*)sp;
    f32x4 b = *(const f32x4*)(sp + 4);
    bf16x8 o;
#pragma unroll
    for (int e = 0; e < 4; ++e) { o[e] = (bf16)a[e]; o[4 + e] = (bf16)b[e]; }
    *(bf16x8*)dst = o;
  } else {
    *(bf16x8*)dst = *(const bf16x8*)((const bf16*)s.p[idx] + i);
  }
}

// =====================================================================
// GEMM v6 = r6-verified structure + XCD-aware tile remap.
// C[M,N] = act(A[M,K] @ B[N,K]^T + bias), bf16, fp32 accum.
// MODE 0: plain, MODE 1: bias+LeakyReLU(0.01), MODE 2: bias only.
// BK=64, XOR-swizzled LDS (SQ_LDS_BANK_CONFLICT=0, r6), single-buffer
// async global_load_lds (r6: best measured; dbuf r8 and hoisting r7
// both regressed). Remap: block id -> (xcd=id&7, slot=id>>3),
// lin = xcd*(nblk/8)+slot, so each XCD owns a contiguous tile band ->
// A-rows/B-cols stay in that XCD's L2 (attacks the 3.7x FETCH overfetch
// + ~900cyc HBM-latency stalls behind MfmaUtil 23%/VALU 40%/HBM 30%).
// Requires gridDim.x*gridDim.y % 8 == 0 (all our grids qualify).
// =====================================================================
template<int MODE, int TM, int TN>
__global__ __launch_bounds__(256)
void gemm_bt(const bf16* __restrict__ A, const bf16* __restrict__ B,
             const bf16* __restrict__ bias, bf16* __restrict__ C,
             int M, int N, int K)
{
  constexpr int MI = TM / 32;
  constexpr int NJ = TN / 32;
  __shared__ __attribute__((aligned(16))) bf16 As[TM * 64];
  __shared__ __attribute__((aligned(16))) bf16 Bs[TN * 64];

  const int t    = threadIdx.x;
  const int wave = t >> 6;
  const int lane = t & 63;
  const int quad = lane >> 4;
  const int l15  = lane & 15;
  const int wr   = (wave >> 1) * (TM / 2);
  const int wc   = (wave & 1) * (TN / 2);

  // ---- XCD-aware tile remap ----
  const int id    = blockIdx.y * gridDim.x + blockIdx.x;
  const int chunk = (gridDim.x * gridDim.y) >> 3;
  const int lin   = (id & 7) * chunk + (id >> 3);
  const int m0    = (lin / gridDim.x) * TM;
  const int n0    = (lin % gridDim.x) * TN;

  const f32x4 fz = {0.f, 0.f, 0.f, 0.f};
  f32x4 acc[MI][NJ];
#pragma unroll
  for (int i = 0; i < MI; ++i)
#pragma unroll
    for (int j = 0; j < NJ; ++j) acc[i][j] = fz;

  const int nkt = K >> 6;
  for (int kt = 0; kt < nkt; ++kt) {
    const int k0 = kt << 6;
    __syncthreads();   // prior tile's LDS reads done
#pragma unroll
    for (int c = 0; c < TM / 32; ++c) {
      const int s   = c * 256 + t;
      const int row = s >> 3;
      const int kg  = ((s & 7) ^ (row & 7)) << 3;   // source-side swizzle
      async_copy16(A + (size_t)(m0 + row) * K + k0 + kg,
                   As + ((c * 256 + wave * 64) << 3));
    }
#pragma unroll
    for (int c = 0; c < TN / 32; ++c) {
      const int s   = c * 256 + t;
      const int row = s >> 3;
      const int kg  = ((s & 7) ^ (row & 7)) << 3;
      async_copy16(B + (size_t)(n0 + row) * K + k0 + kg,
                   Bs + ((c * 256 + wave * 64) << 3));
    }
    __syncthreads();   // drains vmcnt(0): staged data visible

#pragma unroll
    for (int ks = 0; ks < 2; ++ks) {
      bf16x8 af[MI], bfv[NJ];
#pragma unroll
      for (int i = 0; i < MI; ++i) {
        const int row = wr + i * 16 + l15;
        const int ph  = (ks * 4 + quad) ^ (row & 7);
        af[i] = *(const bf16x8*)(As + row * 64 + ph * 8);
      }
#pragma unroll
      for (int j = 0; j < NJ; ++j) {
        const int row = wc + j * 16 + l15;
        const int ph  = (ks * 4 + quad) ^ (row & 7);
        bfv[j] = *(const bf16x8*)(Bs + row * 64 + ph * 8);
      }
#pragma unroll
      for (int i = 0; i < MI; ++i)
#pragma unroll
        for (int j = 0; j < NJ; ++j)
          acc[i][j] = __builtin_amdgcn_mfma_f32_16x16x32_bf16(af[i], bfv[j],
                                                              acc[i][j], 0, 0, 0);
    }
  }

#pragma unroll
  for (int i = 0; i < MI; ++i) {
    const int m = m0 + wr + i * 16 + quad * 4;
#pragma unroll
    for (int j = 0; j < NJ; ++j) {
      const int n = n0 + wc + j * 16 + l15;
      float bv = 0.f;
      if (MODE >= 1) bv = (float)bias[n];
#pragma unroll
      for (int r = 0; r < 4; ++r) {
        float v = acc[i][j][r];
        if (MODE >= 1) v += bv;
        if (MODE == 1) v = v > 0.f ? v : 0.01f * v;
        C[(size_t)(m + r) * N + n] = (bf16)v;
      }
    }
  }
}

// =====================================================================
// Flash attention v3.1 (r7, unchanged): static softmax (scores ~N(0,1),
// verified absmax 0.031), XCD-aware block map.
// =====================================================================
__global__ __launch_bounds__(256, 4)
void flash_attn(const bf16* __restrict__ Qp, const bf16* __restrict__ Kp,
                const bf16* __restrict__ Vp, bf16* __restrict__ Op,
                const int* __restrict__ vlen, int per_query, int sq, int skv)
{
  __shared__ __attribute__((aligned(16))) bf16 Ks[64][72];
  __shared__ __attribute__((aligned(16))) bf16 VsT[64][72];   // [d][k]
  __shared__ __attribute__((aligned(16))) bf16 Ps[4][32][72]; // per-wave [q][k]
  __shared__ int vlmax_sh;

  const int t    = threadIdx.x;
  const int wave = t >> 6;
  const int lane = t & 63;
  const int quad = lane >> 4;
  const int l15  = lane & 15;
  const int bx   = blockIdx.x;
  const int qt   = bx >> 8;          // 0..3 (slowest)
  const int h    = bx & 7;
  const int b    = (bx >> 3) & 31;
  const int q0   = qt * 128 + wave * 32;

  bf16x8 qfrag[2][2];
#pragma unroll
  for (int mt = 0; mt < 2; ++mt)
#pragma unroll
    for (int ks = 0; ks < 2; ++ks)
      qfrag[mt][ks] = *(const bf16x8*)(Qp +
          (size_t)(b * 512 + q0 + mt * 16 + l15) * sq + h * 64 + ks * 32 + quad * 8);

  int vl_r[2][4];
  int myvl = 1;
#pragma unroll
  for (int mt = 0; mt < 2; ++mt)
#pragma unroll
    for (int r = 0; r < 4; ++r) {
      const int q = q0 + mt * 16 + quad * 4 + r;
      const int v = per_query ? vlen[b * 512 + q] : vlen[b];
      vl_r[mt][r] = v;
      myvl = v > myvl ? v : myvl;
    }

  if (t == 0) vlmax_sh = 1;
  __syncthreads();
#pragma unroll
  for (int off = 1; off < 64; off <<= 1) {
    const int o = __shfl_xor(myvl, off);
    myvl = o > myvl ? o : myvl;
  }
  if (lane == 0) atomicMax(&vlmax_sh, myvl);
  __syncthreads();
  const int ktiles = (vlmax_sh + 63) >> 6;

  const f32x4 fz = {0.f, 0.f, 0.f, 0.f};
  float l_part[2][4] = {{0.f,0.f,0.f,0.f},{0.f,0.f,0.f,0.f}};
  f32x4 o_acc[2][4];
#pragma unroll
  for (int mt = 0; mt < 2; ++mt)
#pragma unroll
    for (int nt = 0; nt < 4; ++nt) o_acc[mt][nt] = fz;

  for (int kt = 0; kt < ktiles; ++kt) {
    const int k0 = kt * 64;
    __syncthreads();   // prior K/V tiles fully consumed
    {
      const int r0 = t >> 3;
      const int c0 = (t & 7) * 8;
      const bf16* g = Kp + (size_t)(b * 512 + k0 + r0) * skv + h * 64 + c0;
      *(bf16x8*)&Ks[r0][c0]      = *(const bf16x8*)g;
      *(bf16x8*)&Ks[r0 + 32][c0] = *(const bf16x8*)(g + (size_t)32 * skv);
    }
    {
      const bf16* g = Vp + (size_t)(b * 512 + k0 + wave * 16) * skv + h * 64 + lane;
      bf16x8 lo, hi;
#pragma unroll
      for (int kk = 0; kk < 8; ++kk) lo[kk] = g[(size_t)kk * skv];
#pragma unroll
      for (int kk = 0; kk < 8; ++kk) hi[kk] = g[(size_t)(kk + 8) * skv];
      *(bf16x8*)&VsT[lane][wave * 16]     = lo;
      *(bf16x8*)&VsT[lane][wave * 16 + 8] = hi;
    }
    __syncthreads();

    // ---- QK^T ----
    f32x4 s[2][4];
#pragma unroll
    for (int mt = 0; mt < 2; ++mt)
#pragma unroll
      for (int nt = 0; nt < 4; ++nt) s[mt][nt] = fz;
#pragma unroll
    for (int ks = 0; ks < 2; ++ks)
#pragma unroll
      for (int nt = 0; nt < 4; ++nt) {
        const bf16x8 bk = *(const bf16x8*)&Ks[nt * 16 + l15][ks * 32 + quad * 8];
        s[0][nt] = __builtin_amdgcn_mfma_f32_16x16x32_bf16(qfrag[0][ks], bk, s[0][nt], 0, 0, 0);
        s[1][nt] = __builtin_amdgcn_mfma_f32_16x16x32_bf16(qfrag[1][ks], bk, s[1][nt], 0, 0, 0);
      }

    // ---- static softmax: p = masked ? 0 : exp(s/8); accumulate l ----
#pragma unroll
    for (int mt = 0; mt < 2; ++mt)
#pragma unroll
      for (int nt = 0; nt < 4; ++nt) {
        const int k_abs = k0 + nt * 16 + l15;
#pragma unroll
        for (int r = 0; r < 4; ++r) {
          const float p = (k_abs < vl_r[mt][r]) ? __expf(s[mt][nt][r] * 0.125f) : 0.f;
          l_part[mt][r] += p;
          Ps[wave][mt * 16 + quad * 4 + r][nt * 16 + l15] = (bf16)p;
        }
      }

    // ---- O += P @ V (Ps per-wave; same-wave DS ordering suffices) ----
#pragma unroll
    for (int ks = 0; ks < 2; ++ks) {
      const bf16x8 ap0 = *(const bf16x8*)&Ps[wave][l15][ks * 32 + quad * 8];
      const bf16x8 ap1 = *(const bf16x8*)&Ps[wave][16 + l15][ks * 32 + quad * 8];
#pragma unroll
      for (int nt = 0; nt < 4; ++nt) {
        const bf16x8 bv = *(const bf16x8*)&VsT[nt * 16 + l15][ks * 32 + quad * 8];
        o_acc[0][nt] = __builtin_amdgcn_mfma_f32_16x16x32_bf16(ap0, bv, o_acc[0][nt], 0, 0, 0);
        o_acc[1][nt] = __builtin_amdgcn_mfma_f32_16x16x32_bf16(ap1, bv, o_acc[1][nt], 0, 0, 0);
      }
    }
  }

  // ---- epilogue ----
#pragma unroll
  for (int mt = 0; mt < 2; ++mt)
#pragma unroll
    for (int r = 0; r < 4; ++r) {
      float l = l_part[mt][r];
#pragma unroll
      for (int off = 1; off < 16; off <<= 1)
        l += __shfl_xor(l, off);
      const float inv_l = (l > 0.f) ? (1.f / l) : 0.f;
      const int q = q0 + mt * 16 + quad * 4 + r;
#pragma unroll
      for (int nt = 0; nt < 4; ++nt)
        Op[(size_t)(b * 512 + q) * 512 + h * 64 + nt * 16 + l15] =
            (bf16)(o_acc[mt][nt][r] * inv_l);
    }
}

// =====================================================================
// AddNorm (internal, bf16 out). One wave per 512-row. In-place safe.
// =====================================================================
__global__ __launch_bounds__(256)
void add_layernorm(const bf16* X, const bf16* R,
                   const bf16* __restrict__ gamma, const bf16* __restrict__ beta,
                   bf16* Out)
{
  const int t    = threadIdx.x;
  const int wave = t >> 6;
  const int lane = t & 63;
  const size_t row  = (size_t)blockIdx.x * 4 + wave;
  const size_t base = row * 512 + lane * 8;

  bf16x8 xv = *(const bf16x8*)(X + base);
  bf16x8 rv = *(const bf16x8*)(R + base);
  float v[8];
  float sum = 0.f, ss = 0.f;
#pragma unroll
  for (int i = 0; i < 8; ++i) {
    v[i] = (float)xv[i] + (float)rv[i];
    sum += v[i];
    ss  += v[i] * v[i];
  }
#pragma unroll
  for (int off = 1; off < 64; off <<= 1) {
    sum += __shfl_xor(sum, off);
    ss  += __shfl_xor(ss, off);
  }
  const float mean = sum * (1.f / 512.f);
  const float var  = ss * (1.f / 512.f) - mean * mean;
  const float rstd = rsqrtf(var + 1e-5f);

  bf16x8 gv = *(const bf16x8*)(gamma + lane * 8);
  bf16x8 bv = *(const bf16x8*)(beta + lane * 8);
  bf16x8 ov;
#pragma unroll
  for (int i = 0; i < 8; ++i)
    ov[i] = (bf16)(((v[i] - mean) * rstd) * (float)gv[i] + (float)bv[i]);
  *(bf16x8*)(Out + base) = ov;
}

// =====================================================================
// Final AddNorm: writes d_out as fp32 or bf16 per the inline dtype probe.
// =====================================================================
__global__ __launch_bounds__(256)
void add_layernorm_out(const bf16* X, const bf16* R,
                       const bf16* __restrict__ gamma, const bf16* __restrict__ beta,
                       void* Out, const u16* __restrict__ xprobe)
{
  const int t    = threadIdx.x;
  const int wave = t >> 6;
  const int lane = t & 63;
  const size_t row  = (size_t)blockIdx.x * 4 + wave;
  const size_t base = row * 512 + lane * 8;

  const int f32 = is_f32(xprobe);

  bf16x8 xv = *(const bf16x8*)(X + base);
  bf16x8 rv = *(const bf16x8*)(R + base);
  float v[8];
  float sum = 0.f, ss = 0.f;
#pragma unroll
  for (int i = 0; i < 8; ++i) {
    v[i] = (float)xv[i] + (float)rv[i];
    sum += v[i];
    ss  += v[i] * v[i];
  }
#pragma unroll
  for (int off = 1; off < 64; off <<= 1) {
    sum += __shfl_xor(sum, off);
    ss  += __shfl_xor(ss, off);
  }
  const float mean = sum * (1.f / 512.f);
  const float var  = ss * (1.f / 512.f) - mean * mean;
  const float rstd = rsqrtf(var + 1e-5f);

  bf16x8 gv = *(const bf16x8*)(gamma + lane * 8);
  bf16x8 bv = *(const bf16x8*)(beta + lane * 8);
  float o[8];
#pragma unroll
  for (int i = 0; i < 8; ++i)
    o[i] = ((v[i] - mean) * rstd) * (float)gv[i] + (float)bv[i];

  if (f32) {
    float* op = (float*)Out + base;
    f32x4 o0 = {o[0], o[1], o[2], o[3]};
    f32x4 o1 = {o[4], o[5], o[6], o[7]};
    *(f32x4*)op       = o0;
    *(f32x4*)(op + 4) = o1;
  } else {
    bf16x8 ov;
#pragma unroll
    for (int i = 0; i < 8; ++i) ov[i] = (bf16)o[i];
    *(bf16x8*)((bf16*)Out + base) = ov;
  }
}

// =====================================================================
extern "C" void kernel_launch(void* const* d_in, const int* in_sizes, int n_in,
                              void* d_out, int out_size, void* d_ws, size_t ws_size,
                              hipStream_t stream)
{
  (void)in_sizes; (void)n_in; (void)out_size; (void)ws_size;

  const int* dvl = (const int*)d_in[2];
  const int* evl = (const int*)d_in[3];
  const u16* xprobe = (const u16*)d_in[0];

  bf16* ws = (bf16*)d_ws;
  bf16* S0 = ws;                 // QKV packed / FFN hidden (S0..S3)
  bf16* S1 = ws + 1 * MD;
  bf16* S3 = ws + 3 * MD;        // attention output O
  bf16* S4 = ws + 4 * MD;        // Y then Z (in-place LN)
  bf16* Xb = ws + 5 * MD;        // X bf16; reused as FFN2 output
  bf16* Eb = ws + 6 * MD;
  bf16* W  = ws + 7 * MD;
  const bf16 *Wq1 = W,
             *Wo1 = W + 786432,   *Wq2 = W + 1048576, *Wk2 = W + 1310720,
             *Wo2 = W + 1835008,
             *W1  = W + 2097152,  *b1  = W + 3145728,
             *W2  = W + 3147776,  *b2  = W + 4196352,
             *g1  = W + 4196864,  *be1 = W + 4197376,
             *g2  = W + 4197888,  *be2 = W + 4198400,
             *g3  = W + 4198912,  *be3 = W + 4199424;

  // ---- ingest (dtype probe inlined per wave) ----
  ConvSrc cs;
  cs.p[0] = d_in[0];  cs.p[1] = d_in[1];
  for (int k = 0; k < 12; ++k) cs.p[2 + k] = d_in[4 + k];
  for (int k = 0; k < 6; ++k)  cs.p[14 + k] = d_in[16 + k];
  convert_all<<<dim3(10248), dim3(256), 0, stream>>>(cs, ws, xprobe);

  dim3 blk(256);
  dim3 gP(4, 128);     // N=512
  dim3 gQKV(12, 128);  // N=1536
  dim3 gKV(8, 128);    // N=1024
  dim3 gF1(16, 128);   // N=2048

  // ---- self-attention ----
  gemm_bt<0,128,128><<<gQKV, blk, 0, stream>>>(Xb, Wq1, nullptr, S0, 16384, 1536, 512);
  flash_attn<<<dim3(1024), blk, 0, stream>>>(S0, S0 + 512, S0 + 1024, S3, dvl, 1, 1536, 1536);
  gemm_bt<0,128,128><<<gP, blk, 0, stream>>>(S3, Wo1, nullptr, S1, 16384, 512, 512);
  add_layernorm<<<dim3(4096), blk, 0, stream>>>(Xb, S1, g1, be1, S4);   // Y

  // ---- cross-attention ----
  gemm_bt<0,128,128><<<gP,  blk, 0, stream>>>(S4, Wq2, nullptr, S0, 16384, 512, 512);
  gemm_bt<0,128,128><<<gKV, blk, 0, stream>>>(Eb, Wk2, nullptr, S1, 16384, 1024, 512);
  flash_attn<<<dim3(1024), blk, 0, stream>>>(S0, S1, S1 + 512, S3, evl, 0, 512, 1024);
  gemm_bt<0,128,128><<<gP, blk, 0, stream>>>(S3, Wo2, nullptr, S1, 16384, 512, 512);
  add_layernorm<<<dim3(4096), blk, 0, stream>>>(S4, S1, g2, be2, S4);   // Z

  // ---- FFN ----
  gemm_bt<1,128,128><<<gF1, blk, 0, stream>>>(S4, W1, b1, S0, 16384, 2048, 512);
  gemm_bt<2,128,128><<<gP,  blk, 0, stream>>>(S0, W2, b2, Xb, 16384, 512, 2048);
  add_layernorm_out<<<dim3(4096), blk, 0, stream>>>(S4, Xb, g3, be3, d_out, xprobe);
}